// Round 4
// baseline (449.642 us; speedup 1.0000x reference)
//
#include <hip/hip_runtime.h>
#include <hip/hip_bf16.h>

#define B_ 8
#define L_ 2048
#define D_ 256
#define BK 32
#define PSTR 40
#define NROW (B_*L_)           // 16384
#define NE ((size_t)B_*L_*D_)  // 4194304
#define THR 6.0f               // defer-max threshold: P <= e^6 ~ 403, fp16-safe
#define MINIT (-1e30f)         // finite -inf substitute

typedef __attribute__((ext_vector_type(8))) _Float16 f16x8;
typedef __attribute__((ext_vector_type(4))) _Float16 hf4;
typedef __attribute__((ext_vector_type(4))) float f32x4;

#define MFMA16F(a,b,c) __builtin_amdgcn_mfma_f32_16x16x32_f16((a),(b),(c),0,0,0)
#define NEG_INF (-__builtin_inff())
#define GLL(src,dst) __builtin_amdgcn_global_load_lds( \
    (const __attribute__((address_space(1))) void*)(src), \
    (__attribute__((address_space(3))) void*)(dst), 16, 0, 0)

__device__ __forceinline__ f32x4 fmax4(f32x4 a, f32x4 b){
  f32x4 r;
  r[0]=fmaxf(a[0],b[0]); r[1]=fmaxf(a[1],b[1]);
  r[2]=fmaxf(a[2],b[2]); r[3]=fmaxf(a[3],b[3]);
  return r;
}

// ---- prep: fp32 x -> fp16 x16 (row-major) + vtl (pre-tiled swizzled V^T) ----
__global__ void prep_k(const float* __restrict__ x,
                       _Float16* __restrict__ x16,
                       _Float16* __restrict__ vtl){
  __shared__ _Float16 T[64][258];
  const int t = threadIdx.x;
  const int l0 = blockIdx.x*64, b = blockIdx.y;
  const int r = t>>5, c = (t&31)*8;
  #pragma unroll
  for (int p=0;p<8;++p){
    int row = r + p*8;
    size_t idx = ((size_t)(b*L_ + l0 + row))*D_ + c;
    float4 v0 = *(const float4*)(x + idx);
    float4 v1 = *(const float4*)(x + idx + 4);
    f16x8 h;
    h[0]=(_Float16)v0.x; h[1]=(_Float16)v0.y; h[2]=(_Float16)v0.z; h[3]=(_Float16)v0.w;
    h[4]=(_Float16)v1.x; h[5]=(_Float16)v1.y; h[6]=(_Float16)v1.z; h[7]=(_Float16)v1.w;
    *(f16x8*)(x16 + idx) = h;
    #pragma unroll
    for (int j=0;j<8;++j) T[row][c+j] = h[j];
  }
  __syncthreads();
  _Float16* vb = vtl + ((size_t)(b*64 + blockIdx.x*2))*8192;
  #pragma unroll
  for (int i=0;i<8;++i){
    int n = t + 256*i;
    int q = n & 1023, tile = n>>10;
    int d = q>>2, ph = q&3;
    int kc = ph ^ ((d>>1)&3);
    int k0 = tile*32 + kc*8;
    f16x8 h;
    #pragma unroll
    for (int j=0;j<8;++j) h[j] = T[k0+j][d];
    *(f16x8*)(vb + (size_t)n*8) = h;
  }
}

// ---- single-pass flash, QBLK=32 q-rows/wave, templated key-split ----
// KS=4: grid = 16 x 8 x 4 = 512 blocks = 2 blocks/CU = 2 waves/SIMD (the
// round-3 failure was 1 wave/SIMD at KS=2). Register budget engineered to
// fit 256/wave: address arrays collapsed to klo/lv16 + wave-uniform dof
// (kof[i] == dof[i]+klo algebraically), wave index via readfirstlane.
template<int KS>
__launch_bounds__(256, 2)
__global__ void flash_t(const _Float16* __restrict__ x16,
                        const _Float16* __restrict__ vtl,
                        const int* __restrict__ mask,
                        _Float16* __restrict__ oall,
                        float* __restrict__ mll,
                        float* __restrict__ mm){
  constexpr int KQt  = L_/KS;        // keys per split
  constexpr int NITt = KQt/BK;       // iterations
  __shared__ __attribute__((aligned(16))) _Float16 sK[2][8192];   // 32 KB
  __shared__ __attribute__((aligned(16))) _Float16 sV[2][8192];   // 32 KB
  __shared__ __attribute__((aligned(16))) _Float16 sP[4][32*PSTR];// 10 KB

  const int tid  = threadIdx.x;
  const int wv   = __builtin_amdgcn_readfirstlane(tid >> 6);  // SGPR wave idx
  const int lane = tid & 63;
  const int quad = lane >> 4, l16 = lane & 15;
  const int b = blockIdx.y, z = blockIdx.z;
  const int q0w = blockIdx.x*128 + wv*32;     // 32 q-rows per wave
  const int sw = l16 & 7, vsw = (l16>>1)&3;

  // collapsed staging offsets: kof[i] = dof[i]+klo, vof[i] = dof[i]+lv16,
  // dof[i] = (wv+i*4)*1024 (wave-uniform -> SGPR)
  const int rb = lane >> 5, pk = lane & 31;
  const unsigned klo  = (unsigned)(rb*512 + ((pk ^ ((2*wv + rb)&7))*16));
  const unsigned lv16 = (unsigned)(lane*16);

  // Q fragments for both 16-row halves
  f16x8 qh[2][8];
  {
    const _Float16* qr = x16 + ((size_t)(b*L_ + q0w + l16))*D_;
    #pragma unroll
    for (int ks=0; ks<8; ++ks){
      qh[0][ks] = *(const f16x8*)(qr + ks*32 + quad*8);
      qh[1][ks] = *(const f16x8*)(qr + (size_t)16*D_ + ks*32 + quad*8);
    }
  }
  unsigned long long mb = 0;
  {
    const int* mrow = mask + b*L_ + z*KQt;
    #pragma unroll
    for (int j=0;j<KQt/16;++j)
      mb |= (unsigned long long)(mrow[j*16 + l16] ? 1u : 0u) << j;
  }

  f32x4 M[2];
  M[0] = (f32x4){MINIT,MINIT,MINIT,MINIT};
  M[1] = (f32x4){MINIT,MINIT,MINIT,MINIT};

  const char* kbase = (const char*)x16 + ((size_t)b*L_ + (size_t)z*KQt)*(D_*2);
  const char* vbase = (const char*)vtl + ((size_t)(b*64 + z*(KQt/32)))*16384;

  #pragma unroll
  for (int i=0;i<4;++i){
    const unsigned df = (unsigned)((wv + i*4)*1024);
    GLL(kbase + df + klo,  (char*)sK[0] + df);
    GLL(vbase + df + lv16, (char*)sV[0] + df);
  }

  f32x4 O[2][16], Osum[2];
  #pragma unroll
  for (int qb=0;qb<2;++qb){
    #pragma unroll
    for (int i=0;i<16;i++) O[qb][i] = (f32x4){0.f,0.f,0.f,0.f};
    Osum[qb] = (f32x4){0.f,0.f,0.f,0.f};
  }
  f16x8 ones;
  #pragma unroll
  for (int j=0;j<8;++j) ones[j] = (_Float16)1.0f;

  __syncthreads();   // tile 0 visible

  for (int it=0; it<NITt; ++it){
    if (it+1 < NITt){
      const char* kb2 = kbase + (size_t)(it+1)*16384;
      const char* vb2 = vbase + (size_t)(it+1)*16384;
      char* kd = (char*)sK[(it+1)&1];
      char* vd = (char*)sV[(it+1)&1];
      #pragma unroll
      for (int i=0;i<4;++i){
        const unsigned df = (unsigned)((wv + i*4)*1024);
        GLL(kb2 + df + klo,  kd + df);
        GLL(vb2 + df + lv16, vd + df);
      }
    }
    const _Float16* kb = sK[it&1];
    const _Float16* vb = sV[it&1];

    // ---- S = Q·K^T : 4 tiles (2 q-halves x 2 key-halves) ----
    f32x4 S[2][2];
    S[0][0]=(f32x4){0,0,0,0}; S[0][1]=(f32x4){0,0,0,0};
    S[1][0]=(f32x4){0,0,0,0}; S[1][1]=(f32x4){0,0,0,0};
    #pragma unroll
    for (int ks=0; ks<8; ++ks){
      f16x8 b0 = *(const f16x8*)(kb + (     l16)*256 + (((ks*4+quad)^sw)*8));
      f16x8 b1 = *(const f16x8*)(kb + (16 + l16)*256 + (((ks*4+quad)^sw)*8));
      S[0][0] = MFMA16F(qh[0][ks], b0, S[0][0]);
      S[1][0] = MFMA16F(qh[1][ks], b0, S[1][0]);
      S[0][1] = MFMA16F(qh[0][ks], b1, S[0][1]);
      S[1][1] = MFMA16F(qh[1][ks], b1, S[1][1]);
    }

    // ---- diag zero (q0w and tile base both %32: overlap only when equal) ----
    {
      const int d0 = q0w - (z*KQt + it*BK);
      if (d0 == 0){
        #pragma unroll
        for (int qb=0;qb<2;++qb)
          #pragma unroll
          for (int r=0;r<4;++r)
            S[qb][qb][r] = (l16 == quad*4+r) ? 0.0f : S[qb][qb][r];
      }
    }
    // ---- key padding mask ----
    {
      const unsigned mw = (unsigned)(mb >> (unsigned)(it*2));
      const float mk0 = (mw & 1u) ? NEG_INF : 0.0f;
      const float mk1 = (mw & 2u) ? NEG_INF : 0.0f;
      #pragma unroll
      for (int qb=0;qb<2;++qb)
        #pragma unroll
        for (int r=0;r<4;++r){ S[qb][0][r] += mk0; S[qb][1][r] += mk1; }
    }

    // ---- defer-max check (fast path: no cross-lane, no rescale) ----
    {
      f32x4 t0 = fmax4(S[0][0], S[0][1]);
      f32x4 t1 = fmax4(S[1][0], S[1][1]);
      int ok = 1;
      #pragma unroll
      for (int r=0;r<4;++r){
        ok &= (t0[r] <= M[0][r] + THR);
        ok &= (t1[r] <= M[1][r] + THR);
      }
      if (!__all(ok)){
        #pragma unroll
        for (int off=1; off<16; off<<=1){
          f32x4 o0, o1;
          #pragma unroll
          for (int r=0;r<4;++r){ o0[r]=__shfl_xor(t0[r],off); o1[r]=__shfl_xor(t1[r],off); }
          t0 = fmax4(t0,o0); t1 = fmax4(t1,o1);
        }
        f32x4 mn0 = fmax4(M[0], t0), mn1 = fmax4(M[1], t1);
        float sc0[4], sc1[4];
        #pragma unroll
        for (int r=0;r<4;++r){
          sc0[r] = __expf(M[0][r] - mn0[r]);
          sc1[r] = __expf(M[1][r] - mn1[r]);
        }
        #pragma unroll
        for (int vt=0; vt<16; ++vt){
          #pragma unroll
          for (int r=0;r<4;++r){ O[0][vt][r] *= sc0[r]; O[1][vt][r] *= sc1[r]; }
        }
        #pragma unroll
        for (int r=0;r<4;++r){ Osum[0][r] *= sc0[r]; Osum[1][r] *= sc1[r]; }
        M[0] = mn0; M[1] = mn1;
      }
    }

    // ---- P = exp(S - M) -> sP (fp16), read back as PV A-fragments ----
    #pragma unroll
    for (int qb=0;qb<2;++qb){
      #pragma unroll
      for (int r=0;r<4;++r){
        const int row = qb*16 + quad*4 + r;
        sP[wv][row*PSTR +      l16] = (_Float16)__expf(S[qb][0][r] - M[qb][r]);
        sP[wv][row*PSTR + 16 + l16] = (_Float16)__expf(S[qb][1][r] - M[qb][r]);
      }
    }
    __threadfence_block();
    f16x8 pf0 = *(const f16x8*)(&sP[wv][(     l16)*PSTR + quad*8]);
    f16x8 pf1 = *(const f16x8*)(&sP[wv][(16 + l16)*PSTR + quad*8]);

    // ---- O += P·V : each V fragment feeds both q-halves ----
    #pragma unroll
    for (int vt=0; vt<16; ++vt){
      f16x8 bv = *(const f16x8*)(vb + (vt*16+l16)*32 + ((quad^vsw)*8));
      O[0][vt] = MFMA16F(pf0, bv, O[0][vt]);
      O[1][vt] = MFMA16F(pf1, bv, O[1][vt]);
    }
    Osum[0] = MFMA16F(pf0, ones, Osum[0]);
    Osum[1] = MFMA16F(pf1, ones, Osum[1]);

    __syncthreads();   // buffer reuse safe + next-tile staging drained
  }

  // ---- epilogue: two 16-row groups in the unchanged oall/mll/mm format ----
  #pragma unroll
  for (int qb=0;qb<2;++qb){
    const int u = b*(L_/16) + blockIdx.x*8 + wv*2 + qb;
    _Float16* ob = oall + (size_t)z*NE + (size_t)u*4096;
    #pragma unroll
    for (int vt=0; vt<16; ++vt){
      hf4 hh;
      #pragma unroll
      for (int r=0;r<4;++r) hh[r] = (_Float16)O[qb][vt][r];
      *(hf4*)(ob + vt*256 + lane*4) = hh;
    }
    if (l16 == 0){
      const int row = u*16 + quad*4;
      #pragma unroll
      for (int r=0;r<4;++r){
        mll[z*NROW + row + r] = Osum[qb][r];
        mm [z*NROW + row + r] = M[qb][r];
      }
    }
  }
}

// ---- combine: out = (sum_z e^{m_z-m*} O'_z) / (sum_z e^{m_z-m*} l_z) ----
template<int KS>
__global__ void combine_t(float* __restrict__ out,
                          const _Float16* __restrict__ oall,
                          const float* __restrict__ mll,
                          const float* __restrict__ mm){
  __shared__ float T2[16][260];
  const int t = threadIdx.x, u = blockIdx.x;
  const int quad = (t>>4)&3, l16 = t&15;
  const int row0 = u*16 + quad*4;

  f32x4 mz[KS], lz[KS];
  #pragma unroll
  for (int zc=0; zc<KS; ++zc){
    mz[zc] = *(const f32x4*)(mm  + zc*NROW + row0);
    lz[zc] = *(const f32x4*)(mll + zc*NROW + row0);
  }
  f32x4 ms = mz[0];
  #pragma unroll
  for (int zc=1; zc<KS; ++zc) ms = fmax4(ms, mz[zc]);

  float sc[KS][4];
  f32x4 den = (f32x4){0.f,0.f,0.f,0.f};
  #pragma unroll
  for (int zc=0; zc<KS; ++zc){
    #pragma unroll
    for (int r=0;r<4;++r){
      sc[zc][r] = __expf(mz[zc][r] - ms[r]);
      den[r] += sc[zc][r] * lz[zc][r];
    }
  }
  float inv[4];
  #pragma unroll
  for (int r=0;r<4;++r) inv[r] = 1.0f/den[r];

  #pragma unroll
  for (int i=0;i<4;++i){
    const int f = t + 256*i;
    const int vt = f>>6;
    float acc[4] = {0.f,0.f,0.f,0.f};
    #pragma unroll
    for (int zc=0; zc<KS; ++zc){
      hf4 v = *(const hf4*)(oall + (size_t)zc*NE + (size_t)u*4096 + (size_t)f*4);
      #pragma unroll
      for (int r=0;r<4;++r) acc[r] += sc[zc][r] * (float)v[r];
    }
    #pragma unroll
    for (int r=0;r<4;++r) T2[quad*4+r][vt*16+l16] = acc[r]*inv[r];
  }
  __syncthreads();
  #pragma unroll
  for (int p=0;p<4;++p){
    const int row = (t>>6) + p*4, col = (t&63)*4;
    float4 vv = *(const float4*)&T2[row][col];
    *(float4*)(out + ((size_t)u*16 + row)*D_ + col) = vv;
  }
}

extern "C" void kernel_launch(void* const* d_in, const int* in_sizes, int n_in,
                              void* d_out, int out_size, void* d_ws, size_t ws_size,
                              hipStream_t stream) {
  const float* x    = (const float*)d_in[0];
  const int*   mask = (const int*)d_in[1];
  float*       out  = (float*)d_out;

  _Float16* x16  = (_Float16*)d_ws;
  _Float16* vtl  = x16 + NE;
  _Float16* oall = vtl + NE;

  // workspace need at KS=4: 16 MB (x16+vtl) + 32 MB (oall) + 0.5 MB = ~48.5 MB
  const size_t need4 = (2*NE + 4*NE)*sizeof(_Float16) + (size_t)2*4*NROW*sizeof(float);

  prep_k<<<dim3(L_/64, B_), dim3(256), 0, stream>>>(x, x16, vtl);

  if (ws_size == 0 || ws_size >= need4){
    float* mll = (float*)(oall + (size_t)4*NE);
    float* mm  = mll + (size_t)4*NROW;
    flash_t<4><<<dim3(L_/128, B_, 4), dim3(256), 0, stream>>>(x16, vtl, mask, oall, mll, mm);
    combine_t<4><<<dim3(NROW/16), dim3(256), 0, stream>>>(out, oall, mll, mm);
  } else {
    float* mll = (float*)(oall + (size_t)2*NE);
    float* mm  = mll + (size_t)2*NROW;
    flash_t<2><<<dim3(L_/128, B_, 2), dim3(256), 0, stream>>>(x16, vtl, mask, oall, mll, mm);
    combine_t<2><<<dim3(NROW/16), dim3(256), 0, stream>>>(out, oall, mll, mm);
  }
}

// Round 5
// 145.693 us; speedup vs baseline: 3.0862x; 3.0862x over previous
//
#include <hip/hip_runtime.h>
#include <hip/hip_bf16.h>

#define B_ 8
#define L_ 2048
#define D_ 256
#define BK 32
#define KSPLIT 2
#define KQ (L_/KSPLIT)         // 1024 keys per split
#define NIT (KQ/BK)            // 32 iterations
#define PSTR 40
#define NROW (B_*L_)           // 16384
#define NE ((size_t)B_*L_*D_)  // 4194304
#define THR 6.0f               // defer-max threshold: P <= e^6 ~ 403, fp16-safe
#define MINIT (-1e30f)         // finite -inf substitute

typedef __attribute__((ext_vector_type(8))) _Float16 f16x8;
typedef __attribute__((ext_vector_type(4))) _Float16 hf4;
typedef __attribute__((ext_vector_type(4))) float f32x4;

#define MFMA16F(a,b,c) __builtin_amdgcn_mfma_f32_16x16x32_f16((a),(b),(c),0,0,0)
#define NEG_INF (-__builtin_inff())
#define GLL(src,dst) __builtin_amdgcn_global_load_lds( \
    (const __attribute__((address_space(1))) void*)(src), \
    (__attribute__((address_space(3))) void*)(dst), 16, 0, 0)

__device__ __forceinline__ f32x4 fmax4(f32x4 a, f32x4 b){
  f32x4 r;
  r[0]=fmaxf(a[0],b[0]); r[1]=fmaxf(a[1],b[1]);
  r[2]=fmaxf(a[2],b[2]); r[3]=fmaxf(a[3],b[3]);
  return r;
}

// ---- prep: fp32 x -> fp16 x16 (row-major) + vtl (pre-tiled swizzled V^T) ----
__global__ void prep_k(const float* __restrict__ x,
                       _Float16* __restrict__ x16,
                       _Float16* __restrict__ vtl){
  __shared__ _Float16 T[64][258];
  const int t = threadIdx.x;
  const int l0 = blockIdx.x*64, b = blockIdx.y;
  const int r = t>>5, c = (t&31)*8;
  #pragma unroll
  for (int p=0;p<8;++p){
    int row = r + p*8;
    size_t idx = ((size_t)(b*L_ + l0 + row))*D_ + c;
    float4 v0 = *(const float4*)(x + idx);
    float4 v1 = *(const float4*)(x + idx + 4);
    f16x8 h;
    h[0]=(_Float16)v0.x; h[1]=(_Float16)v0.y; h[2]=(_Float16)v0.z; h[3]=(_Float16)v0.w;
    h[4]=(_Float16)v1.x; h[5]=(_Float16)v1.y; h[6]=(_Float16)v1.z; h[7]=(_Float16)v1.w;
    *(f16x8*)(x16 + idx) = h;
    #pragma unroll
    for (int j=0;j<8;++j) T[row][c+j] = h[j];
  }
  __syncthreads();
  _Float16* vb = vtl + ((size_t)(b*64 + blockIdx.x*2))*8192;
  #pragma unroll
  for (int i=0;i<8;++i){
    int n = t + 256*i;
    int q = n & 1023, tile = n>>10;
    int d = q>>2, ph = q&3;
    int kc = ph ^ ((d>>1)&3);
    int k0 = tile*32 + kc*8;
    f16x8 h;
    #pragma unroll
    for (int j=0;j<8;++j) h[j] = T[k0+j][d];
    *(f16x8*)(vb + (size_t)n*8) = h;
  }
}

// ---- single-pass flash, QBLK=16, one-tile P/V software pipeline ----
// Iteration t: QK(t) -> PV(t-1) -> softmax(t) -> write sP[t&1] -> barrier.
// PV(t-1)'s operands (sP[(t-1)&1], sV[(t-1)&1]) are ready at iter start, so
// its 18 ds_reads issue before/under the softmax VALU chain instead of after
// it (round-1's serialization). The sP roundtrip crosses a barrier, not a
// threadfence. PV(t-1) precedes the defer-check rescale at t, so O contains
// all tiles < t whenever M updates (correct online softmax).
// V staged at distance 1: stage V_t at iter t, consume at iter t+1.
__launch_bounds__(256, 2)
__global__ void flash_k(const _Float16* __restrict__ x16,
                        const _Float16* __restrict__ vtl,
                        const int* __restrict__ mask,
                        _Float16* __restrict__ oall,
                        float* __restrict__ mll,
                        float* __restrict__ mm){
  __shared__ __attribute__((aligned(16))) _Float16 sK[2][8192];     // 32 KB
  __shared__ __attribute__((aligned(16))) _Float16 sV[2][8192];     // 32 KB
  __shared__ __attribute__((aligned(16))) _Float16 sP[2][4][16*PSTR];// 10 KB

  const int tid  = threadIdx.x;
  const int wave = tid >> 6, lane = tid & 63;
  const int quad = lane >> 4, l16 = lane & 15;
  const int b = blockIdx.y, z = blockIdx.z;
  const int q0w = blockIdx.x*64 + wave*16;
  const int sw = l16 & 7, vsw = (l16>>1)&3;

  f16x8 qh[8];
  {
    const _Float16* qr = x16 + ((size_t)(b*L_ + q0w + l16))*D_;
    #pragma unroll
    for (int ks=0; ks<8; ++ks)
      qh[ks] = *(const f16x8*)(qr + ks*32 + quad*8);
  }
  unsigned long long mb = 0;
  {
    const int* mrow = mask + b*L_ + z*KQ;
    #pragma unroll
    for (int j=0;j<64;++j)
      mb |= (unsigned long long)(mrow[j*16 + l16] ? 1u : 0u) << j;
  }

  f32x4 M = (f32x4){MINIT, MINIT, MINIT, MINIT};

  unsigned kof[4], vof[4], dof[4];
  #pragma unroll
  for (int i=0;i<4;++i){
    int c = (wave + i*4)*64 + lane;
    int r = c>>5, pk = c&31;
    kof[i] = (unsigned)(r*512 + ((pk ^ (r&7))*16));
    vof[i] = (unsigned)(c*16);
    dof[i] = (unsigned)((wave + i*4)*1024);
  }
  const char* kbase = (const char*)x16 + ((size_t)b*L_ + (size_t)z*KQ)*(D_*2);
  const char* vbase = (const char*)vtl + ((size_t)(b*64 + z*32))*16384;

  // prologue: K_0 only (V_0 is staged at the top of iter 0)
  #pragma unroll
  for (int i=0;i<4;++i) GLL(kbase + kof[i], (char*)sK[0] + dof[i]);

  f32x4 O[16], Osum;
  #pragma unroll
  for (int i=0;i<16;i++) O[i] = (f32x4){0.f,0.f,0.f,0.f};
  Osum = (f32x4){0.f,0.f,0.f,0.f};
  f16x8 ones;
  #pragma unroll
  for (int j=0;j<8;++j) ones[j] = (_Float16)1.0f;

  __syncthreads();   // K_0 visible

  for (int it=0; it<NIT; ++it){
    // ---- stage K_{t+1} and V_t ----
    if (it+1 < NIT){
      const char* kb2 = kbase + (size_t)(it+1)*16384;
      char* kd = (char*)sK[(it+1)&1];
      #pragma unroll
      for (int i=0;i<4;++i) GLL(kb2 + kof[i], kd + dof[i]);
    }
    {
      const char* vb2 = vbase + (size_t)it*16384;
      char* vd = (char*)sV[it&1];
      #pragma unroll
      for (int i=0;i<4;++i) GLL(vb2 + vof[i], vd + dof[i]);
    }
    const _Float16* kb = sK[it&1];

    // ---- S = Q·K^T (tile t) ----
    f32x4 S[2];
    S[0]=(f32x4){0,0,0,0}; S[1]=(f32x4){0,0,0,0};
    #pragma unroll
    for (int ks=0; ks<8; ++ks){
      f16x8 b0 = *(const f16x8*)(kb + (     l16)*256 + (((ks*4+quad)^sw)*8));
      f16x8 b1 = *(const f16x8*)(kb + (16 + l16)*256 + (((ks*4+quad)^sw)*8));
      S[0] = MFMA16F(qh[ks], b0, S[0]);
      S[1] = MFMA16F(qh[ks], b1, S[1]);
    }

    // ---- PV (tile t-1): operands ready since last barrier ----
    if (it > 0){
      const _Float16* vb = sV[(it-1)&1];
      f16x8 pf = *(const f16x8*)(&sP[(it-1)&1][wave][l16*PSTR + quad*8]);
      #pragma unroll
      for (int vt=0; vt<16; ++vt){
        f16x8 bv = *(const f16x8*)(vb + (vt*16+l16)*32 + ((quad^vsw)*8));
        O[vt] = MFMA16F(pf, bv, O[vt]);
      }
      Osum = MFMA16F(pf, ones, Osum);
    }

    // ---- diag zero, then key padding mask (tile t) ----
    {
      const int d0 = q0w - (z*KQ + it*BK);
      if ((unsigned)d0 < 32u){
        const int ntd = d0 >> 4;
        #pragma unroll
        for (int r=0;r<4;++r)
          S[ntd][r] = (l16 == quad*4+r) ? 0.0f : S[ntd][r];
      }
    }
    {
      const unsigned mw = (unsigned)(mb >> (unsigned)(it*2));
      const float mk0 = (mw & 1u) ? NEG_INF : 0.0f;
      const float mk1 = (mw & 2u) ? NEG_INF : 0.0f;
      #pragma unroll
      for (int r=0;r<4;++r){ S[0][r] += mk0; S[1][r] += mk1; }
    }

    // ---- defer-max check; rescale covers all tiles < t (PV t-1 done) ----
    {
      f32x4 t = fmax4(S[0], S[1]);
      int ok = 1;
      #pragma unroll
      for (int r=0;r<4;++r) ok &= (t[r] <= M[r] + THR);
      if (!__all(ok)){
        #pragma unroll
        for (int off=1; off<16; off<<=1){
          f32x4 o;
          o[0]=__shfl_xor(t[0],off); o[1]=__shfl_xor(t[1],off);
          o[2]=__shfl_xor(t[2],off); o[3]=__shfl_xor(t[3],off);
          t = fmax4(t,o);
        }
        f32x4 mn = fmax4(M, t);
        float sc[4];
        #pragma unroll
        for (int r=0;r<4;++r) sc[r] = __expf(M[r] - mn[r]);
        #pragma unroll
        for (int vt=0; vt<16; ++vt){
          #pragma unroll
          for (int r=0;r<4;++r) O[vt][r] *= sc[r];
        }
        #pragma unroll
        for (int r=0;r<4;++r) Osum[r] *= sc[r];
        M = mn;
      }
    }

    // ---- P = exp(S - M) -> sP[t&1]; consumed next iteration ----
    #pragma unroll
    for (int r=0;r<4;++r){
      const int row = quad*4 + r;
      sP[it&1][wave][row*PSTR +      l16] = (_Float16)__expf(S[0][r] - M[r]);
      sP[it&1][wave][row*PSTR + 16 + l16] = (_Float16)__expf(S[1][r] - M[r]);
    }

    __syncthreads();   // sP/sV(t) visible for t+1; staging drained
  }

  // ---- drain: PV for the last tile ----
  {
    const _Float16* vb = sV[(NIT-1)&1];
    f16x8 pf = *(const f16x8*)(&sP[(NIT-1)&1][wave][l16*PSTR + quad*8]);
    #pragma unroll
    for (int vt=0; vt<16; ++vt){
      f16x8 bv = *(const f16x8*)(vb + (vt*16+l16)*32 + ((quad^vsw)*8));
      O[vt] = MFMA16F(pf, bv, O[vt]);
    }
    Osum = MFMA16F(pf, ones, Osum);
  }

  // ---- epilogue: fragment-major fp16 partial O' + partial l + running m ----
  {
    const int u = b*(L_/16) + blockIdx.x*4 + wave;
    _Float16* ob = oall + (size_t)z*NE + (size_t)u*4096;
    #pragma unroll
    for (int vt=0; vt<16; ++vt){
      hf4 hh;
      #pragma unroll
      for (int r=0;r<4;++r) hh[r] = (_Float16)O[vt][r];
      *(hf4*)(ob + vt*256 + lane*4) = hh;
    }
    if (l16 == 0){
      const int row = u*16 + quad*4;
      #pragma unroll
      for (int r=0;r<4;++r){
        mll[z*NROW + row + r] = Osum[r];
        mm [z*NROW + row + r] = M[r];
      }
    }
  }
}

// ---- combine: out = (sum_z e^{m_z-m*} O'_z) / (sum_z e^{m_z-m*} l_z) ----
__global__ void combine_k(float* __restrict__ out,
                          const _Float16* __restrict__ oall,
                          const float* __restrict__ mll,
                          const float* __restrict__ mm){
  __shared__ float T2[16][260];
  const int t = threadIdx.x, u = blockIdx.x;
  const int quad = (t>>4)&3, l16 = t&15;
  const int row0 = u*16 + quad*4;

  f32x4 mz[KSPLIT], lz[KSPLIT];
  #pragma unroll
  for (int zc=0; zc<KSPLIT; ++zc){
    mz[zc] = *(const f32x4*)(mm  + zc*NROW + row0);
    lz[zc] = *(const f32x4*)(mll + zc*NROW + row0);
  }
  f32x4 ms = mz[0];
  #pragma unroll
  for (int zc=1; zc<KSPLIT; ++zc) ms = fmax4(ms, mz[zc]);

  float sc[KSPLIT][4];
  f32x4 den = (f32x4){0.f,0.f,0.f,0.f};
  #pragma unroll
  for (int zc=0; zc<KSPLIT; ++zc){
    #pragma unroll
    for (int r=0;r<4;++r){
      sc[zc][r] = __expf(mz[zc][r] - ms[r]);
      den[r] += sc[zc][r] * lz[zc][r];
    }
  }
  float inv[4];
  #pragma unroll
  for (int r=0;r<4;++r) inv[r] = 1.0f/den[r];

  #pragma unroll
  for (int i=0;i<4;++i){
    const int f = t + 256*i;
    const int vt = f>>6;
    float acc[4] = {0.f,0.f,0.f,0.f};
    #pragma unroll
    for (int zc=0; zc<KSPLIT; ++zc){
      hf4 v = *(const hf4*)(oall + (size_t)zc*NE + (size_t)u*4096 + (size_t)f*4);
      #pragma unroll
      for (int r=0;r<4;++r) acc[r] += sc[zc][r] * (float)v[r];
    }
    #pragma unroll
    for (int r=0;r<4;++r) T2[quad*4+r][vt*16+l16] = acc[r]*inv[r];
  }
  __syncthreads();
  #pragma unroll
  for (int p=0;p<4;++p){
    const int row = (t>>6) + p*4, col = (t&63)*4;
    float4 vv = *(const float4*)&T2[row][col];
    *(float4*)(out + ((size_t)u*16 + row)*D_ + col) = vv;
  }
}

extern "C" void kernel_launch(void* const* d_in, const int* in_sizes, int n_in,
                              void* d_out, int out_size, void* d_ws, size_t ws_size,
                              hipStream_t stream) {
  const float* x    = (const float*)d_in[0];
  const int*   mask = (const int*)d_in[1];
  float*       out  = (float*)d_out;

  _Float16* x16  = (_Float16*)d_ws;
  _Float16* vtl  = x16 + NE;
  _Float16* oall = vtl + NE;                       // KSPLIT*NE fp16
  float*    mll  = (float*)(oall + (size_t)KSPLIT*NE);
  float*    mm   = mll + (size_t)KSPLIT*NROW;

  prep_k   <<<dim3(L_/64, B_), dim3(256), 0, stream>>>(x, x16, vtl);
  flash_k  <<<dim3(L_/64, B_, KSPLIT), dim3(256), 0, stream>>>(x16, vtl, mask, oall, mll, mm);
  combine_k<<<dim3(NROW/16), dim3(256), 0, stream>>>(out, oall, mll, mm);
}